// Round 2
// baseline (467.043 us; speedup 1.0000x reference)
//
#include <hip/hip_runtime.h>

#define W 512
#define IMG (512 * 512)
#define NIMG 256  // 8 * 32

// Kernel A: per image, fused "identity copy of non-pyramid region" + level-0
// conv+downsample. One thread per level-0 output pixel (i,j) in [0,256)^2,
// owning input 2x2 block at (2i, 2j). Reads x exactly once; writes out once.
__global__ __launch_bounds__(256) void kA(const float* __restrict__ x,
                                          float* __restrict__ out) {
    const int gid = blockIdx.x;
    const int img = gid >> 8;        // 256 blocks per image
    const int b   = gid & 255;
    const int tid = threadIdx.x;
    // block covers i-range of 4 (one row per wave), j-range of 64 (lanes)
    const int i = (b >> 2) * 4 + (tid >> 6);
    const int j = (b & 3) * 64 + (tid & 63);

    const float* xi = x + (size_t)img * IMG;
    float* oi = out + (size_t)img * IMG;

    const int r0 = 2 * i - 1, r1 = 2 * i, r2 = 2 * i + 1;
    const int c0 = 2 * j - 1;

    // owned coalesced loads (rows r1, r2 at col 2j), halo row r0 + halo col c0
    float2 m1 = *(const float2*)(xi + r1 * W + 2 * j);
    float2 m2 = *(const float2*)(xi + r2 * W + 2 * j);
    float2 m0 = (r0 >= 0) ? *(const float2*)(xi + r0 * W + 2 * j)
                          : make_float2(0.f, 0.f);
    float l0 = (r0 >= 0 && c0 >= 0) ? xi[r0 * W + c0] : 0.f;
    float l1 = (c0 >= 0) ? xi[r1 * W + c0] : 0.f;
    float l2 = (c0 >= 0) ? xi[r2 * W + c0] : 0.f;

    // separable 3x3: horizontal [.25,.5,.25] then vertical
    float h0 = 0.25f * l0 + 0.5f * m0.x + 0.25f * m0.y;
    float h1 = 0.25f * l1 + 0.5f * m1.x + 0.25f * m1.y;
    float h2 = 0.25f * l2 + 0.5f * m2.x + 0.25f * m2.y;
    oi[i * W + j] = 0.25f * h0 + 0.5f * h1 + 0.25f * h2;

    // identity copy for the 2x2 block when outside top-left 256x256 quarter.
    // (j is 64-wide per wave so j>=128 is wave-uniform; i is wave-uniform)
    if (i >= 128 || j >= 128) {
        *(float2*)(oi + r1 * W + 2 * j) = m1;
        *(float2*)(oi + r2 * W + 2 * j) = m2;
    }
}

// Kernel BC: levels 1 and 2 fused, one block per image. Phase 1 computes the
// 128x128 level-1 conv from global `out` (level-0 result, visible across the
// kernel boundary) into LDS; no global writes before the barrier, so no RW
// hazard. Phase 2 writes LDS to out[0:128)^2 except [0:64)^2, which gets the
// level-2 conv computed from LDS.
__global__ __launch_bounds__(1024) void kBC(float* __restrict__ out) {
    __shared__ float S1[128][128];  // 64 KiB
    const int img = blockIdx.x;
    float* oi = out + (size_t)img * IMG;
    const int tid = threadIdx.x;
    const int j = tid & 127;
    const int i0 = tid >> 7;  // 0..7

    // ---- phase 1: level-1 conv over out[0:256)^2 -> S1[128][128]
    for (int k = 0; k < 16; ++k) {
        const int i = i0 + 8 * k;  // 0..127
        const int r0 = 2 * i - 1, r1 = 2 * i, r2 = 2 * i + 1;
        const int c0 = 2 * j - 1;
        float2 m1 = *(const float2*)(oi + r1 * W + 2 * j);
        float2 m2 = *(const float2*)(oi + r2 * W + 2 * j);
        float2 m0 = (r0 >= 0) ? *(const float2*)(oi + r0 * W + 2 * j)
                              : make_float2(0.f, 0.f);
        float l0 = (r0 >= 0 && c0 >= 0) ? oi[r0 * W + c0] : 0.f;
        float l1 = (c0 >= 0) ? oi[r1 * W + c0] : 0.f;
        float l2 = (c0 >= 0) ? oi[r2 * W + c0] : 0.f;
        float h0 = 0.25f * l0 + 0.5f * m0.x + 0.25f * m0.y;
        float h1 = 0.25f * l1 + 0.5f * m1.x + 0.25f * m1.y;
        float h2 = 0.25f * l2 + 0.5f * m2.x + 0.25f * m2.y;
        S1[i][j] = 0.25f * h0 + 0.5f * h1 + 0.25f * h2;
    }
    __syncthreads();

    // ---- phase 2a: S1 -> out[0:128)^2 minus the level-2 region [0:64)^2
    for (int k = 0; k < 16; ++k) {
        const int i = i0 + 8 * k;
        if (i >= 64 || j >= 64) oi[i * W + j] = S1[i][j];
    }

    // ---- phase 2b: level-2 conv from S1 -> out[0:64)^2 (reads LDS only,
    // writes a region disjoint from 2a — no extra barrier needed)
    const int j2 = tid & 63;
    const int ib = tid >> 6;  // 0..15
    for (int k = 0; k < 4; ++k) {
        const int i = ib + 16 * k;  // 0..63
        const int r0 = 2 * i - 1, r1 = 2 * i, r2 = 2 * i + 1;
        const int c0 = 2 * j2 - 1;
        float m1x = S1[r1][2 * j2], m1y = S1[r1][2 * j2 + 1];
        float m2x = S1[r2][2 * j2], m2y = S1[r2][2 * j2 + 1];
        float m0x = (r0 >= 0) ? S1[r0][2 * j2] : 0.f;
        float m0y = (r0 >= 0) ? S1[r0][2 * j2 + 1] : 0.f;
        float l0 = (r0 >= 0 && c0 >= 0) ? S1[r0][c0] : 0.f;
        float l1 = (c0 >= 0) ? S1[r1][c0] : 0.f;
        float l2 = (c0 >= 0) ? S1[r2][c0] : 0.f;
        float h0 = 0.25f * l0 + 0.5f * m0x + 0.25f * m0y;
        float h1 = 0.25f * l1 + 0.5f * m1x + 0.25f * m1y;
        float h2 = 0.25f * l2 + 0.5f * m2x + 0.25f * m2y;
        oi[i * W + j2] = 0.25f * h0 + 0.5f * h1 + 0.25f * h2;
    }
}

extern "C" void kernel_launch(void* const* d_in, const int* in_sizes, int n_in,
                              void* d_out, int out_size, void* d_ws,
                              size_t ws_size, hipStream_t stream) {
    const float* x = (const float*)d_in[0];
    float* out = (float*)d_out;
    (void)in_sizes; (void)n_in; (void)d_ws; (void)ws_size; (void)out_size;

    // Kernel A: 256 blocks/image * 256 images
    kA<<<NIMG * 256, 256, 0, stream>>>(x, out);
    // Kernel BC: one block per image
    kBC<<<NIMG, 1024, 0, stream>>>(out);
}

// Round 3
// 457.701 us; speedup vs baseline: 1.0204x; 1.0204x over previous
//
#include <hip/hip_runtime.h>

#define W 512
#define IMG (512 * 512)
#define NIMG 256  // 8 * 32
#define L1SZ (128 * 128)

// ---------------------------------------------------------------------------
// Kernel A: fused identity-copy + level-0 conv/downsample.
// One thread owns a 2x4 input block (rows 2i..2i+1, cols 4jq..4jq+3) and
// produces 2 conv outputs (i, 2jq), (i, 2jq+1). Left halo comes from the
// previous lane via __shfl_up (memory load only for lane 0 at a wave seam).
// 128 blocks/image: b>>1 selects i-quad (4 rows/block), b&1 selects jq half.
// ---------------------------------------------------------------------------
__global__ __launch_bounds__(256) void kA(const float* __restrict__ x,
                                          float* __restrict__ out) {
    const int gid = blockIdx.x;
    const int img = gid >> 7;  // 128 blocks per image
    const int b   = gid & 127;
    const int tid = threadIdx.x;
    const int lane = tid & 63;
    const int i  = (b >> 1) * 4 + (tid >> 6);  // output row 0..255
    const int jq = (b & 1) * 64 + lane;        // col-quad 0..127
    const int c0 = 4 * jq;                     // input col 0..508

    const float* xi = x + (size_t)img * IMG;
    float* oi = out + (size_t)img * IMG;
    const int r0 = 2 * i - 1, r1 = 2 * i, r2 = 2 * i + 1;

    float4 m1 = *(const float4*)(xi + r1 * W + c0);
    float4 m2 = *(const float4*)(xi + r2 * W + c0);
    float4 m0 = (r0 >= 0) ? *(const float4*)(xi + r0 * W + c0)
                          : make_float4(0.f, 0.f, 0.f, 0.f);

    // left halo x[r][c0-1]: previous lane's .w (r0<0 is wave-uniform -> m0=0
    // for all lanes, so the shfl correctly propagates 0)
    float p0 = __shfl_up(m0.w, 1, 64);
    float p1 = __shfl_up(m1.w, 1, 64);
    float p2 = __shfl_up(m2.w, 1, 64);
    if (lane == 0) {
        if (c0 == 0) {
            p0 = p1 = p2 = 0.f;
        } else {  // wave seam at c0=256
            p1 = xi[r1 * W + c0 - 1];
            p2 = xi[r2 * W + c0 - 1];
            p0 = (r0 >= 0) ? xi[r0 * W + c0 - 1] : 0.f;
        }
    }

    // horizontal [.25,.5,.25] at centers c0 and c0+2, then vertical
    float ha0 = 0.25f * p0 + 0.5f * m0.x + 0.25f * m0.y;
    float hb0 = 0.25f * m0.y + 0.5f * m0.z + 0.25f * m0.w;
    float ha1 = 0.25f * p1 + 0.5f * m1.x + 0.25f * m1.y;
    float hb1 = 0.25f * m1.y + 0.5f * m1.z + 0.25f * m1.w;
    float ha2 = 0.25f * p2 + 0.5f * m2.x + 0.25f * m2.y;
    float hb2 = 0.25f * m2.y + 0.5f * m2.z + 0.25f * m2.w;
    float2 o;
    o.x = 0.25f * ha0 + 0.5f * ha1 + 0.25f * ha2;
    o.y = 0.25f * hb0 + 0.5f * hb1 + 0.25f * hb2;
    *(float2*)(oi + i * W + 2 * jq) = o;

    // identity copy when the owned 2x4 block is outside the 256x256 quarter
    // (i>=128 wave-uniform; jq>=64 <=> b&1, block-uniform)
    if (i >= 128 || jq >= 64) {
        *(float4*)(oi + r1 * W + c0) = m1;
        *(float4*)(oi + r2 * W + c0) = m2;
    }
}

// ---------------------------------------------------------------------------
// Kernel B: level-1 conv/downsample. Reads out[0:256)^2 (level-0 result),
// writes 128x128 per image into ws. 32 blocks/image, wave = one output row.
// ---------------------------------------------------------------------------
__global__ __launch_bounds__(256) void kB(const float* __restrict__ out,
                                          float* __restrict__ ws) {
    const int gid = blockIdx.x;
    const int img = gid >> 5;  // 32 blocks per image
    const int b   = gid & 31;
    const int tid = threadIdx.x;
    const int lane = tid & 63;
    const int i  = b * 4 + (tid >> 6);  // output row 0..127
    const int c0 = 4 * lane;            // input col 0..252

    const float* oi = out + (size_t)img * IMG;
    float* wsi = ws + (size_t)img * L1SZ;
    const int r0 = 2 * i - 1, r1 = 2 * i, r2 = 2 * i + 1;

    float4 m1 = *(const float4*)(oi + r1 * W + c0);
    float4 m2 = *(const float4*)(oi + r2 * W + c0);
    float4 m0 = (r0 >= 0) ? *(const float4*)(oi + r0 * W + c0)
                          : make_float4(0.f, 0.f, 0.f, 0.f);
    float p0 = __shfl_up(m0.w, 1, 64);
    float p1 = __shfl_up(m1.w, 1, 64);
    float p2 = __shfl_up(m2.w, 1, 64);
    if (lane == 0) { p0 = p1 = p2 = 0.f; }  // c0==0: zero pad

    float ha0 = 0.25f * p0 + 0.5f * m0.x + 0.25f * m0.y;
    float hb0 = 0.25f * m0.y + 0.5f * m0.z + 0.25f * m0.w;
    float ha1 = 0.25f * p1 + 0.5f * m1.x + 0.25f * m1.y;
    float hb1 = 0.25f * m1.y + 0.5f * m1.z + 0.25f * m1.w;
    float ha2 = 0.25f * p2 + 0.5f * m2.x + 0.25f * m2.y;
    float hb2 = 0.25f * m2.y + 0.5f * m2.z + 0.25f * m2.w;
    float2 o;
    o.x = 0.25f * ha0 + 0.5f * ha1 + 0.25f * ha2;
    o.y = 0.25f * hb0 + 0.5f * hb1 + 0.25f * hb2;
    *(float2*)(wsi + i * 128 + 2 * lane) = o;
}

// ---------------------------------------------------------------------------
// Kernel C: identity-copy ws -> out[0:128)^2 (outside [0:64)^2) + level-2
// conv from ws into out[0:64)^2. Thread owns a 2x4 ws block; 8 blocks/image.
// tid>>5 = row-pair sub-index, tid&31 = col-quad.
// ---------------------------------------------------------------------------
__global__ __launch_bounds__(256) void kC(const float* __restrict__ ws,
                                          float* __restrict__ out) {
    const int gid = blockIdx.x;
    const int img = gid >> 3;  // 8 blocks per image
    const int b   = gid & 7;
    const int tid = threadIdx.x;
    const int i2  = b * 8 + (tid >> 5);  // conv output row 0..63
    const int jq2 = tid & 31;            // col-quad 0..31
    const int c0  = 4 * jq2;             // ws col 0..124

    const float* wsi = ws + (size_t)img * L1SZ;
    float* oi = out + (size_t)img * IMG;
    const int r0 = 2 * i2 - 1, r1 = 2 * i2, r2 = 2 * i2 + 1;

    float4 m1 = *(const float4*)(wsi + r1 * 128 + c0);
    float4 m2 = *(const float4*)(wsi + r2 * 128 + c0);
    float4 m0 = (r0 >= 0) ? *(const float4*)(wsi + r0 * 128 + c0)
                          : make_float4(0.f, 0.f, 0.f, 0.f);
    // left halo: lanes with (tid&31)==0 have c0==0 -> zero pad; shfl_up
    // crosses the lane-32 sub-row seam but that lane has c0==0 and is fixed.
    float p0 = __shfl_up(m0.w, 1, 64);
    float p1 = __shfl_up(m1.w, 1, 64);
    float p2 = __shfl_up(m2.w, 1, 64);
    if (jq2 == 0) { p0 = p1 = p2 = 0.f; }

    float ha0 = 0.25f * p0 + 0.5f * m0.x + 0.25f * m0.y;
    float hb0 = 0.25f * m0.y + 0.5f * m0.z + 0.25f * m0.w;
    float ha1 = 0.25f * p1 + 0.5f * m1.x + 0.25f * m1.y;
    float hb1 = 0.25f * m1.y + 0.5f * m1.z + 0.25f * m1.w;
    float ha2 = 0.25f * p2 + 0.5f * m2.x + 0.25f * m2.y;
    float hb2 = 0.25f * m2.y + 0.5f * m2.z + 0.25f * m2.w;
    float2 o;
    o.x = 0.25f * ha0 + 0.5f * ha1 + 0.25f * ha2;
    o.y = 0.25f * hb0 + 0.5f * hb1 + 0.25f * hb2;
    *(float2*)(oi + i2 * W + 2 * jq2) = o;

    // identity ws -> out for the owned 2x4 block when outside [0:64)^2
    // (r1>=64 <=> i2>=32, uniform per 32-lane group; c0>=64 <=> jq2>=16)
    if (r1 >= 64 || c0 >= 64) {
        *(float4*)(oi + r1 * W + c0) = m1;
        *(float4*)(oi + r2 * W + c0) = m2;
    }
}

extern "C" void kernel_launch(void* const* d_in, const int* in_sizes, int n_in,
                              void* d_out, int out_size, void* d_ws,
                              size_t ws_size, hipStream_t stream) {
    const float* x = (const float*)d_in[0];
    float* out = (float*)d_out;
    float* ws = (float*)d_ws;  // needs 256*128*128*4 = 16 MiB
    (void)in_sizes; (void)n_in; (void)ws_size; (void)out_size;

    kA<<<NIMG * 128, 256, 0, stream>>>(x, out);
    kB<<<NIMG * 32, 256, 0, stream>>>(out, ws);
    kC<<<NIMG * 8, 256, 0, stream>>>(ws, out);
}

// Round 5
// 449.339 us; speedup vs baseline: 1.0394x; 1.0186x over previous
//
#include <hip/hip_runtime.h>

#define W 512
#define IMG (512 * 512)
#define NIMG 256  // 8 * 32

// ---------------------------------------------------------------------------
// Kernel A (unchanged — passed, likely BW-bound):
// fused identity-copy + level-0 conv/downsample. One thread owns a 2x4 input
// block (rows 2i..2i+1, cols 4jq..4jq+3), produces 2 conv outputs.
// ---------------------------------------------------------------------------
__global__ __launch_bounds__(256) void kA(const float* __restrict__ x,
                                          float* __restrict__ out) {
    const int gid = blockIdx.x;
    const int img = gid >> 7;  // 128 blocks per image
    const int b   = gid & 127;
    const int tid = threadIdx.x;
    const int lane = tid & 63;
    const int i  = (b >> 1) * 4 + (tid >> 6);  // output row 0..255
    const int jq = (b & 1) * 64 + lane;        // col-quad 0..127
    const int c0 = 4 * jq;                     // input col 0..508

    const float* xi = x + (size_t)img * IMG;
    float* oi = out + (size_t)img * IMG;
    const int r0 = 2 * i - 1, r1 = 2 * i, r2 = 2 * i + 1;

    float4 m1 = *(const float4*)(xi + r1 * W + c0);
    float4 m2 = *(const float4*)(xi + r2 * W + c0);
    float4 m0 = (r0 >= 0) ? *(const float4*)(xi + r0 * W + c0)
                          : make_float4(0.f, 0.f, 0.f, 0.f);

    float p0 = __shfl_up(m0.w, 1, 64);
    float p1 = __shfl_up(m1.w, 1, 64);
    float p2 = __shfl_up(m2.w, 1, 64);
    if (lane == 0) {
        if (c0 == 0) {
            p0 = p1 = p2 = 0.f;
        } else {  // wave seam at c0=256
            p1 = xi[r1 * W + c0 - 1];
            p2 = xi[r2 * W + c0 - 1];
            p0 = (r0 >= 0) ? xi[r0 * W + c0 - 1] : 0.f;
        }
    }

    float ha0 = 0.25f * p0 + 0.5f * m0.x + 0.25f * m0.y;
    float hb0 = 0.25f * m0.y + 0.5f * m0.z + 0.25f * m0.w;
    float ha1 = 0.25f * p1 + 0.5f * m1.x + 0.25f * m1.y;
    float hb1 = 0.25f * m1.y + 0.5f * m1.z + 0.25f * m1.w;
    float ha2 = 0.25f * p2 + 0.5f * m2.x + 0.25f * m2.y;
    float hb2 = 0.25f * m2.y + 0.5f * m2.z + 0.25f * m2.w;
    float2 o;
    o.x = 0.25f * ha0 + 0.5f * ha1 + 0.25f * ha2;
    o.y = 0.25f * hb0 + 0.5f * hb1 + 0.25f * hb2;
    *(float2*)(oi + i * W + 2 * jq) = o;

    if (i >= 128 || jq >= 64) {
        *(float4*)(oi + r1 * W + c0) = m1;
        *(float4*)(oi + r2 * W + c0) = m2;
    }
}

// ---------------------------------------------------------------------------
// Kernel BC2: levels 1+2 fused, one block per image, 1024 threads.
// Phase 1: level-1 conv from out[0:256)^2 (level-0, visible across the kernel
//   boundary) into LDS S1 (padded stride 132 -> no bank conflicts in 2b).
//   No global writes before the barrier -> no RW hazard on out.
// Phase 2a: S1 -> out[0:128)^2 minus [0:64)^2 (float4 stores).
// Phase 2b: level-2 conv from S1 -> out[0:64)^2 (disjoint region, no barrier
//   needed vs 2a).
// ---------------------------------------------------------------------------
#define S1P 132
__global__ __launch_bounds__(1024) void kBC2(float* __restrict__ out) {
    __shared__ float S1[128 * S1P];  // 66 KiB
    const int img = blockIdx.x;
    float* oi = out + (size_t)img * IMG;
    const int tid = threadIdx.x;
    const int lane = tid & 63;
    const int wv = tid >> 6;  // 0..15

    // ---- phase 1: level-1 conv (float4 + shfl halo), wave = one output row
    for (int k = 0; k < 8; ++k) {
        const int i = wv + 16 * k;  // 0..127
        const int r0 = 2 * i - 1, r1 = 2 * i, r2 = 2 * i + 1;
        const int c0 = 4 * lane;  // 0..252
        float4 m1 = *(const float4*)(oi + r1 * W + c0);
        float4 m2 = *(const float4*)(oi + r2 * W + c0);
        float4 m0 = (r0 >= 0) ? *(const float4*)(oi + r0 * W + c0)
                              : make_float4(0.f, 0.f, 0.f, 0.f);
        float p0 = __shfl_up(m0.w, 1, 64);
        float p1 = __shfl_up(m1.w, 1, 64);
        float p2 = __shfl_up(m2.w, 1, 64);
        if (lane == 0) { p0 = p1 = p2 = 0.f; }
        float ha0 = 0.25f * p0 + 0.5f * m0.x + 0.25f * m0.y;
        float hb0 = 0.25f * m0.y + 0.5f * m0.z + 0.25f * m0.w;
        float ha1 = 0.25f * p1 + 0.5f * m1.x + 0.25f * m1.y;
        float hb1 = 0.25f * m1.y + 0.5f * m1.z + 0.25f * m1.w;
        float ha2 = 0.25f * p2 + 0.5f * m2.x + 0.25f * m2.y;
        float hb2 = 0.25f * m2.y + 0.5f * m2.z + 0.25f * m2.w;
        float2 o;
        o.x = 0.25f * ha0 + 0.5f * ha1 + 0.25f * ha2;
        o.y = 0.25f * hb0 + 0.5f * hb1 + 0.25f * hb2;
        *(float2*)(&S1[i * S1P + 2 * lane]) = o;
    }
    __syncthreads();

    // ---- phase 2a: S1 -> out[0:128)^2 minus [0:64)^2, float4 per thread
    for (int k = 0; k < 4; ++k) {
        const int idx = tid + 1024 * k;     // 0..4095
        const int row = idx >> 5;           // 0..127
        const int cq  = (idx & 31) * 4;     // 0..124
        if (row >= 64 || cq >= 64) {
            *(float4*)(oi + row * W + cq) = *(const float4*)(&S1[row * S1P + cq]);
        }
    }

    // ---- phase 2b: level-2 conv from S1 -> out[0:64)^2
    {
        const int r  = tid >> 4;            // 0..63
        const int cb = (tid & 15) * 8;      // input col base 0..120
        const int r0 = 2 * r - 1, r1 = 2 * r, r2 = 2 * r + 1;
        float h[3][4];
        for (int s = 0; s < 3; ++s) {
            const int rr = (s == 0) ? r0 : (s == 1) ? r1 : r2;
            if (rr < 0) {
                h[s][0] = h[s][1] = h[s][2] = h[s][3] = 0.f;
            } else {
                const float* Sr = &S1[rr * S1P];
                float left = (cb == 0) ? 0.f : Sr[cb - 1];
                #pragma unroll
                for (int q = 0; q < 4; ++q) {
                    const int c = cb + 2 * q;
                    float a = (q == 0) ? left : Sr[c - 1];
                    h[s][q] = 0.25f * a + 0.5f * Sr[c] + 0.25f * Sr[c + 1];
                }
            }
        }
        float4 o;
        o.x = 0.25f * h[0][0] + 0.5f * h[1][0] + 0.25f * h[2][0];
        o.y = 0.25f * h[0][1] + 0.5f * h[1][1] + 0.25f * h[2][1];
        o.z = 0.25f * h[0][2] + 0.5f * h[1][2] + 0.25f * h[2][2];
        o.w = 0.25f * h[0][3] + 0.5f * h[1][3] + 0.25f * h[2][3];
        *(float4*)(oi + r * W + (tid & 15) * 4) = o;
    }
}

extern "C" void kernel_launch(void* const* d_in, const int* in_sizes, int n_in,
                              void* d_out, int out_size, void* d_ws,
                              size_t ws_size, hipStream_t stream) {
    const float* x = (const float*)d_in[0];
    float* out = (float*)d_out;
    (void)in_sizes; (void)n_in; (void)d_ws; (void)ws_size; (void)out_size;

    kA<<<NIMG * 128, 256, 0, stream>>>(x, out);
    kBC2<<<NIMG, 1024, 0, stream>>>(out);
}